// Round 4
// baseline (1161.277 us; speedup 1.0000x reference)
//
#include <hip/hip_runtime.h>

#define BLOCK 512
#define RPB   128          // rows per block: 128 quads x 1 row
#define WPS   260          // Wp LDS row stride (floats): 260%32=4 -> quad lanes on distinct banks
#define WS    36           // 32x32 weight LDS row stride (floats): 36%32=4 -> conflict-free b128

// chained FMA: acc = acc + dot(x4, w4) as 4 serial v_fma (no extra mul/add)
#define FMA4(ACC_, X_, W_) \
    ACC_ = fmaf((X_).x, (W_).x, ACC_); ACC_ = fmaf((X_).y, (W_).y, ACC_); \
    ACC_ = fmaf((X_).z, (W_).z, ACC_); ACC_ = fmaf((X_).w, (W_).w, ACC_);

// out[d] = sum_j W[d][j]*in[j] for this lane's 8 outputs d = q+4e (full 32-dot via 4
// quad_perm phases). W stored with permuted columns: col j at (j&3)*8 + (j>>2), so the
// slice held by lane (q^p) (elements j = (q^p)+4j') is contiguous -> float4 reads.
__device__ __forceinline__ void matvec32(const float* __restrict__ WL, const int q,
                                         const float* __restrict__ in, float* __restrict__ outv)
{
    #pragma unroll
    for (int e = 0; e < 8; ++e) outv[e] = 0.f;
    #pragma unroll
    for (int p = 0; p < 4; ++p) {
        float xs[8];
        #pragma unroll
        for (int j = 0; j < 8; ++j)            // quad_perm DPP, compile-time mask
            xs[j] = (p == 0) ? in[j] : __shfl_xor(in[j], p);
        const float* wb = WL + q * WS + (q ^ p) * 8;
        #pragma unroll
        for (int e = 0; e < 8; ++e) {          // banks 4q+8(q^p)+16e -> distinct across quad
            float4 w0 = *(const float4*)(wb + e * (4 * WS));
            float4 w1 = *(const float4*)(wb + e * (4 * WS) + 4);
            float t = outv[e];
            t = fmaf(w0.x, xs[0], t); t = fmaf(w0.y, xs[1], t);
            t = fmaf(w0.z, xs[2], t); t = fmaf(w0.w, xs[3], t);
            t = fmaf(w1.x, xs[4], t); t = fmaf(w1.y, xs[5], t);
            t = fmaf(w1.z, xs[6], t); t = fmaf(w1.w, xs[7], t);
            outv[e] = t;
        }
    }
}

__launch_bounds__(BLOCK, 4)   // 4 waves/EU -> VGPR cap 128
__global__ void msfe_kernel(
    const float* __restrict__ f1, const float* __restrict__ f4, const float* __restrict__ fD,
    const float* __restrict__ Wp, const float* __restrict__ bp,
    const float* __restrict__ ln_g, const float* __restrict__ ln_b,
    const float* __restrict__ Wq, const float* __restrict__ bq,
    const float* __restrict__ Wk, const float* __restrict__ bk,
    const float* __restrict__ Wv, const float* __restrict__ bv,
    const float* __restrict__ Wo1, const float* __restrict__ bo1,
    const float* __restrict__ Wo2, const float* __restrict__ bo2,
    float* __restrict__ out, int nRows)
{
    __shared__ float Wp_l[32 * WPS];                       // 33.3 KB, padded stride
    __shared__ float A_l[32 * WS];                         // Wq^T Wk / sqrt(D), permuted cols
    __shared__ float Wv_l[32 * WS], Wo1_l[32 * WS], Wo2_l[32 * WS];  // permuted cols
    __shared__ float obuf[RPB * 32];                       // 16 KB store-coalescing bounce
    __shared__ float bp_l[32], g_l[32], b_l[32], u_l[32], v_l[32];
    __shared__ float bv_l[32], bo1_l[32], bo2_l[32];
    __shared__ float c_l;

    const int tid = threadIdx.x;
    const float isq = 0.17677669529663688f;  // 1/sqrt(32)

    // ---- stage Wp: [32][256] -> stride-260 rows (coalesced float4) ----
    #pragma unroll
    for (int i = 0; i < 4; ++i) {
        int idx = tid + i * BLOCK;                 // float4 index 0..2047
        int d = idx >> 6, k4 = idx & 63;
        *(float4*)&Wp_l[d * WPS + 4 * k4] = ((const float4*)Wp)[idx];
    }
    if (tid < 256) {
        // ---- stage Wv/Wo1/Wo2 with permuted columns: elem m of float4 j4 -> col' m*8+j4 ----
        int d = tid >> 3, j4 = tid & 7;
        float4 wv = ((const float4*)Wv )[tid];
        float4 w1 = ((const float4*)Wo1)[tid];
        float4 w2 = ((const float4*)Wo2)[tid];
        float* pv = &Wv_l [d * WS + j4];
        float* p1 = &Wo1_l[d * WS + j4];
        float* p2 = &Wo2_l[d * WS + j4];
        pv[0] = wv.x; pv[8] = wv.y; pv[16] = wv.z; pv[24] = wv.w;
        p1[0] = w1.x; p1[8] = w1.y; p1[16] = w1.z; p1[24] = w1.w;
        p2[0] = w2.x; p2[8] = w2.y; p2[16] = w2.z; p2[24] = w2.w;
        // ---- A = Wq^T Wk * isq (permuted cols), from global (L2-resident) ----
        int a = d, b4 = j4;
        float s0 = 0.f, s1 = 0.f, s2 = 0.f, s3 = 0.f;
        #pragma unroll 8
        for (int dd = 0; dd < 32; ++dd) {
            float  wq = Wq[dd * 32 + a];
            float4 wk = *(const float4*)&Wk[dd * 32 + 4 * b4];
            s0 = fmaf(wq, wk.x, s0); s1 = fmaf(wq, wk.y, s1);
            s2 = fmaf(wq, wk.z, s2); s3 = fmaf(wq, wk.w, s3);
        }
        float* pa = &A_l[a * WS + b4];
        pa[0] = s0 * isq; pa[8] = s1 * isq; pa[16] = s2 * isq; pa[24] = s3 * isq;
    } else if (tid < 288) {                        // u = (Wk^T bq) * isq
        int a = tid - 256; float s = 0.f;
        #pragma unroll 8
        for (int d = 0; d < 32; ++d) s = fmaf(bq[d], Wk[d * 32 + a], s);
        u_l[a] = s * isq;
    } else if (tid < 320) {                        // v = (Wq^T bk) * isq
        int a = tid - 288; float s = 0.f;
        #pragma unroll 8
        for (int d = 0; d < 32; ++d) s = fmaf(Wq[d * 32 + a], bk[d], s);
        v_l[a] = s * isq;
    } else if (tid == 320) {                       // c = bq.bk * isq
        float s = 0.f;
        #pragma unroll 8
        for (int d = 0; d < 32; ++d) s = fmaf(bq[d], bk[d], s);
        c_l = s * isq;
    } else if (tid >= 480) {
        int a = tid - 480;
        bp_l[a] = bp[a]; g_l[a] = ln_g[a]; b_l[a] = ln_b[a];
    } else if (tid >= 448) {
        int a = tid - 448;
        bv_l[a] = bv[a]; bo1_l[a] = bo1[a]; bo2_l[a] = bo2[a];
    }
    __syncthreads();

    // ---- lane mapping: quad q owns interleaved outputs d = q + 4e; 1 row per quad ----
    const int q   = tid & 3;
    const int qid = tid >> 2;                      // row slot within block
    const int row = blockIdx.x * RPB + qid;
    const bool active = (row < nRows);             // no early return: barrier below

    if (active) {
        const size_t rowoff = (size_t)row * 256;
        const float* __restrict__ p0 = f1 + rowoff;
        const float* __restrict__ p1 = f4 + rowoff;
        const float* __restrict__ p2 = fD + rowoff;

        // ---- Phase A: fused 3-stream projection, 2-chunk-deep SW pipeline ----
        float acc0[8], acc1[8], acc2[8];
        #pragma unroll
        for (int e = 0; e < 8; ++e) { acc0[e] = 0.f; acc1[e] = 0.f; acc2[e] = 0.f; }

        // buffer X holds even chunks (kc), buffer Y holds odd chunks (kc+8)
        float4 Xa0 = *(const float4*)(p0),      Xb0 = *(const float4*)(p0 + 4);
        float4 Xa1 = *(const float4*)(p1),      Xb1 = *(const float4*)(p1 + 4);
        float4 Xa2 = *(const float4*)(p2),      Xb2 = *(const float4*)(p2 + 4);
        float4 Ya0 = *(const float4*)(p0 + 8),  Yb0 = *(const float4*)(p0 + 12);
        float4 Ya1 = *(const float4*)(p1 + 8),  Yb1 = *(const float4*)(p1 + 12);
        float4 Ya2 = *(const float4*)(p2 + 8),  Yb2 = *(const float4*)(p2 + 12);

        const float* wbase = &Wp_l[q * WPS];

        #pragma unroll 1
        for (int kc = 0; kc < 256; kc += 16) {
            // -- compute even chunk kc from X --
            {
                const float* wr = wbase + kc;
                #pragma unroll
                for (int e = 0; e < 8; ++e) {      // d = q+4e -> conflict-free, 16x broadcast
                    float4 w0 = *(const float4*)(wr + e * (4 * WPS));
                    float4 w1 = *(const float4*)(wr + e * (4 * WPS) + 4);
                    FMA4(acc0[e], Xa0, w0) FMA4(acc0[e], Xb0, w1)
                    FMA4(acc1[e], Xa1, w0) FMA4(acc1[e], Xb1, w1)
                    FMA4(acc2[e], Xa2, w0) FMA4(acc2[e], Xb2, w1)
                }
            }
            if (kc + 16 < 256) {                   // refill X with chunk kc+16
                Xa0 = *(const float4*)(p0 + kc + 16); Xb0 = *(const float4*)(p0 + kc + 20);
                Xa1 = *(const float4*)(p1 + kc + 16); Xb1 = *(const float4*)(p1 + kc + 20);
                Xa2 = *(const float4*)(p2 + kc + 16); Xb2 = *(const float4*)(p2 + kc + 20);
            }
            // -- compute odd chunk kc+8 from Y --
            {
                const float* wr = wbase + kc + 8;
                #pragma unroll
                for (int e = 0; e < 8; ++e) {
                    float4 w0 = *(const float4*)(wr + e * (4 * WPS));
                    float4 w1 = *(const float4*)(wr + e * (4 * WPS) + 4);
                    FMA4(acc0[e], Ya0, w0) FMA4(acc0[e], Yb0, w1)
                    FMA4(acc1[e], Ya1, w0) FMA4(acc1[e], Yb1, w1)
                    FMA4(acc2[e], Ya2, w0) FMA4(acc2[e], Yb2, w1)
                }
            }
            if (kc + 24 < 256) {                   // refill Y with chunk kc+24
                Ya0 = *(const float4*)(p0 + kc + 24); Yb0 = *(const float4*)(p0 + kc + 28);
                Ya1 = *(const float4*)(p1 + kc + 24); Yb1 = *(const float4*)(p1 + kc + 28);
                Ya2 = *(const float4*)(p2 + kc + 24); Yb2 = *(const float4*)(p2 + kc + 28);
            }
        }

        // ---- bias + ReLU + LayerNorm per stream (quad reduction over 32 dims) ----
        float Xh[3][8];
        float bpe[8], ge[8], be[8];
        #pragma unroll
        for (int e = 0; e < 8; ++e) { bpe[e] = bp_l[q + 4*e]; ge[e] = g_l[q + 4*e]; be[e] = b_l[q + 4*e]; }
        #pragma unroll
        for (int s = 0; s < 3; ++s) {
            float* accp = (s == 0) ? acc0 : (s == 1) ? acc1 : acc2;
            float sm = 0.f, sq = 0.f;
            #pragma unroll
            for (int e = 0; e < 8; ++e) {
                float t = fmaxf(accp[e] + bpe[e], 0.f);
                accp[e] = t; sm += t; sq = fmaf(t, t, sq);
            }
            sm += __shfl_xor(sm, 1); sm += __shfl_xor(sm, 2);
            sq += __shfl_xor(sq, 1); sq += __shfl_xor(sq, 2);
            float mu  = sm * 0.03125f;
            float var = fmaf(-mu, mu, sq * 0.03125f);
            float inv = rsqrtf(var + 1e-5f);
            #pragma unroll
            for (int e = 0; e < 8; ++e)
                Xh[s][e] = fmaf(ge[e] * (accp[e] - mu), inv, be[e]);
        }

        // ---- scores sc[s][t] = X_s^T A X_t + u.X_t + v.X_s + c ----
        float uX[3], vX[3];
        {
            float uq[8], vq[8];
            #pragma unroll
            for (int e = 0; e < 8; ++e) { uq[e] = u_l[q + 4*e]; vq[e] = v_l[q + 4*e]; }
            #pragma unroll
            for (int t = 0; t < 3; ++t) {
                float us = 0.f, vs = 0.f;
                #pragma unroll
                for (int e = 0; e < 8; ++e) {
                    us = fmaf(uq[e], Xh[t][e], us);
                    vs = fmaf(vq[e], Xh[t][e], vs);
                }
                us += __shfl_xor(us, 1); us += __shfl_xor(us, 2);
                vs += __shfl_xor(vs, 1); vs += __shfl_xor(vs, 2);
                uX[t] = us; vX[t] = vs;
            }
        }

        float sc[9];
        #pragma unroll
        for (int t = 0; t < 3; ++t) {
            float y[8];
            matvec32(A_l, q, Xh[t], y);            // y[e] = (A X_t)[q+4e], full dot
            #pragma unroll
            for (int s = 0; s < 3; ++s) {
                float p = 0.f;
                #pragma unroll
                for (int e = 0; e < 8; ++e) p = fmaf(Xh[s][e], y[e], p);
                sc[s * 3 + t] = p;                 // partial over my 8 dims
            }
        }
        #pragma unroll
        for (int s = 0; s < 3; ++s)
            #pragma unroll
            for (int t = 0; t < 3; ++t) {
                float p = sc[s * 3 + t];
                p += __shfl_xor(p, 1); p += __shfl_xor(p, 2);
                sc[s * 3 + t] = p + uX[t] + vX[s] + c_l;
            }

        // ---- softmax rows; fold V through xb = sum_t g_t X_t ----
        float g0 = 0.f, g1 = 0.f, g2 = 0.f;
        #pragma unroll
        for (int s = 0; s < 3; ++s) {
            float a0 = sc[s*3+0], a1 = sc[s*3+1], a2 = sc[s*3+2];
            float m  = fmaxf(a0, fmaxf(a1, a2));
            float e0 = __expf(a0 - m), e1 = __expf(a1 - m), e2 = __expf(a2 - m);
            float r  = 1.f / (e0 + e1 + e2);
            g0 = fmaf(e0, r, g0); g1 = fmaf(e1, r, g1); g2 = fmaf(e2, r, g2);
        }
        g0 *= (1.f/3.f); g1 *= (1.f/3.f); g2 *= (1.f/3.f);

        float xb[8];
        #pragma unroll
        for (int e = 0; e < 8; ++e)
            xb[e] = fmaf(g0, Xh[0][e], fmaf(g1, Xh[1][e], g2 * Xh[2][e]));

        // ---- pooled = Wv xb + bv ; h1 = relu(Wo1 pooled + bo1) ; o = Wo2 h1 + bo2 + pooled ----
        float t8[8], ph[8], hh[8];
        matvec32(Wv_l, q, xb, t8);
        #pragma unroll
        for (int e = 0; e < 8; ++e) ph[e] = t8[e] + bv_l[q + 4 * e];
        matvec32(Wo1_l, q, ph, t8);
        #pragma unroll
        for (int e = 0; e < 8; ++e) hh[e] = fmaxf(t8[e] + bo1_l[q + 4 * e], 0.f);
        matvec32(Wo2_l, q, hh, t8);

        // ---- write row to LDS bounce (XOR-swizzled groups -> 2-way-free banks) ----
        const int s5 = (qid & 7) << 2;
        #pragma unroll
        for (int e = 0; e < 8; ++e) {
            int d = q + 4 * e;
            obuf[qid * 32 + (d ^ s5)] = t8[e] + bo2_l[d] + ph[e];
        }
    }
    __syncthreads();

    // ---- block-cooperative coalesced float4 stores ----
    const int rowBase = blockIdx.x * RPB;
    int nblk = nRows - rowBase; if (nblk > RPB) nblk = RPB;
    for (int t = tid; t < nblk * 8; t += BLOCK) {
        int r = t >> 3, cg = t & 7;
        int g = (cg ^ (r & 7)) << 2;               // undo swizzle
        float4 vv = *(const float4*)&obuf[r * 32 + g];
        *(float4*)(out + (size_t)(rowBase + r) * 32 + cg * 4) = vv;
    }
}

extern "C" void kernel_launch(void* const* d_in, const int* in_sizes, int n_in,
                              void* d_out, int out_size, void* d_ws, size_t ws_size,
                              hipStream_t stream) {
    const float* f1   = (const float*)d_in[0];
    const float* f4   = (const float*)d_in[1];
    const float* fD   = (const float*)d_in[2];
    const float* Wp   = (const float*)d_in[3];
    const float* bp   = (const float*)d_in[4];
    const float* ln_g = (const float*)d_in[5];
    const float* ln_b = (const float*)d_in[6];
    const float* Wq   = (const float*)d_in[7];
    const float* bq   = (const float*)d_in[8];
    const float* Wk   = (const float*)d_in[9];
    const float* bk   = (const float*)d_in[10];
    const float* Wv   = (const float*)d_in[11];
    const float* bv   = (const float*)d_in[12];
    const float* Wo1  = (const float*)d_in[13];
    const float* bo1  = (const float*)d_in[14];
    const float* Wo2  = (const float*)d_in[15];
    const float* bo2  = (const float*)d_in[16];

    const int nRows  = in_sizes[0] / 256;
    const int blocks = (nRows + RPB - 1) / RPB;

    msfe_kernel<<<blocks, BLOCK, 0, stream>>>(
        f1, f4, fD, Wp, bp, ln_g, ln_b, Wq, bq, Wk, bk, Wv, bv,
        Wo1, bo1, Wo2, bo2, (float*)d_out, nRows);
}

// Round 5
// 896.183 us; speedup vs baseline: 1.2958x; 1.2958x over previous
//
#include <hip/hip_runtime.h>

#define BLOCK 512
#define RPB   64           // rows per block: 64 rows x 8 lanes (octet) per row
#define WPS   260          // Wp LDS row stride (floats): 260%32=4 -> octet lanes on distinct banks
#define WS    36           // 32x32 weight LDS row stride (floats): 36%32=4 -> <=2-way (free) conflicts

// chained FMA: acc = acc + dot(x4, w4) as 4 serial v_fma
#define FMA4(ACC_, X_, W_) \
    ACC_ = fmaf((X_).x, (W_).x, ACC_); ACC_ = fmaf((X_).y, (W_).y, ACC_); \
    ACC_ = fmaf((X_).z, (W_).z, ACC_); ACC_ = fmaf((X_).w, (W_).w, ACC_);

// Octet matvec: out[d] = sum_j W[d][j]*in[j]; lane o owns d = o+8e (e<4) and holds
// in[jj] = x[o+8jj]. 8 quad..octet-perm phases; W stored with permuted columns:
// col j at (j&7)*4 + (j>>3), so lane (o^p)'s slice (cols (o^p)+8jj) is one float4.
__device__ __forceinline__ void matvec32(const float* __restrict__ WL, const int o,
                                         const float* __restrict__ in, float* __restrict__ outv)
{
    #pragma unroll
    for (int e = 0; e < 4; ++e) outv[e] = 0.f;
    #pragma unroll
    for (int p = 0; p < 8; ++p) {
        float xs[4];
        #pragma unroll
        for (int jj = 0; jj < 4; ++jj)
            xs[jj] = (p == 0) ? in[jj] : __shfl_xor(in[jj], p);
        const float* wb = WL + o * WS + (o ^ p) * 4;
        #pragma unroll
        for (int e = 0; e < 4; ++e) {      // rows o+8e; banks <=2-way (free) + 8x broadcast
            float4 w = *(const float4*)(wb + e * (8 * WS));
            float t = outv[e];
            t = fmaf(w.x, xs[0], t); t = fmaf(w.y, xs[1], t);
            t = fmaf(w.z, xs[2], t); t = fmaf(w.w, xs[3], t);
            outv[e] = t;
        }
    }
}

__global__ void __launch_bounds__(BLOCK)
__attribute__((amdgpu_waves_per_eu(4, 6)))   // max 6: stop 8-wave/64-reg squeeze (R4 spill)
msfe_kernel(
    const float* __restrict__ f1, const float* __restrict__ f4, const float* __restrict__ fD,
    const float* __restrict__ Wp, const float* __restrict__ bp,
    const float* __restrict__ ln_g, const float* __restrict__ ln_b,
    const float* __restrict__ Wq, const float* __restrict__ bq,
    const float* __restrict__ Wk, const float* __restrict__ bk,
    const float* __restrict__ Wv, const float* __restrict__ bv,
    const float* __restrict__ Wo1, const float* __restrict__ bo1,
    const float* __restrict__ Wo2, const float* __restrict__ bo2,
    float* __restrict__ out, int nRows)
{
    __shared__ float Wp_l[32 * WPS];                       // 33.3 KB, padded stride
    __shared__ float A_l[32 * WS];                         // Wq^T Wk / sqrt(D), permuted cols
    __shared__ float Wv_l[32 * WS], Wo1_l[32 * WS], Wo2_l[32 * WS];  // permuted cols
    __shared__ float bp_l[32], g_l[32], b_l[32], u_l[32], v_l[32];
    __shared__ float bv_l[32], bo1_l[32], bo2_l[32];
    __shared__ float c_l;
    // total 52,740 B -> 53,248 alloc; 3 blocks/CU (159,744 <= 160 KB) = 24 waves/CU

    const int tid = threadIdx.x;
    const float isq = 0.17677669529663688f;  // 1/sqrt(32)

    // ---- stage Wp: [32][256] -> stride-260 rows (coalesced float4) ----
    #pragma unroll
    for (int i = 0; i < 4; ++i) {
        int idx = tid + i * BLOCK;                 // float4 index 0..2047
        int d = idx >> 6, k4 = idx & 63;
        *(float4*)&Wp_l[d * WPS + 4 * k4] = ((const float4*)Wp)[idx];
    }
    if (tid < 256) {
        // ---- stage Wv/Wo1/Wo2, octet col-perm: col j -> (j&7)*4 + (j>>3) ----
        // thread owns row d, float4 j4 (cols 4j4+m): pos = 16*(j4&1) + (j4>>1) + 4m
        int d = tid >> 3, j4 = tid & 7;
        int base = d * WS + 16 * (j4 & 1) + (j4 >> 1);
        float4 wv = ((const float4*)Wv )[tid];
        float4 w1 = ((const float4*)Wo1)[tid];
        float4 w2 = ((const float4*)Wo2)[tid];
        Wv_l [base] = wv.x; Wv_l [base+4] = wv.y; Wv_l [base+8] = wv.z; Wv_l [base+12] = wv.w;
        Wo1_l[base] = w1.x; Wo1_l[base+4] = w1.y; Wo1_l[base+8] = w1.z; Wo1_l[base+12] = w1.w;
        Wo2_l[base] = w2.x; Wo2_l[base+4] = w2.y; Wo2_l[base+8] = w2.z; Wo2_l[base+12] = w2.w;
        // ---- A = Wq^T Wk * isq (same col-perm), from global (L2-resident) ----
        float s0 = 0.f, s1 = 0.f, s2 = 0.f, s3 = 0.f;
        #pragma unroll 8
        for (int dd = 0; dd < 32; ++dd) {
            float  wq = Wq[dd * 32 + d];
            float4 wk = *(const float4*)&Wk[dd * 32 + 4 * j4];
            s0 = fmaf(wq, wk.x, s0); s1 = fmaf(wq, wk.y, s1);
            s2 = fmaf(wq, wk.z, s2); s3 = fmaf(wq, wk.w, s3);
        }
        A_l[base] = s0 * isq; A_l[base+4] = s1 * isq; A_l[base+8] = s2 * isq; A_l[base+12] = s3 * isq;
    } else if (tid < 288) {                        // u = (Wk^T bq) * isq
        int a = tid - 256; float s = 0.f;
        #pragma unroll 8
        for (int d = 0; d < 32; ++d) s = fmaf(bq[d], Wk[d * 32 + a], s);
        u_l[a] = s * isq;
    } else if (tid < 320) {                        // v = (Wq^T bk) * isq
        int a = tid - 288; float s = 0.f;
        #pragma unroll 8
        for (int d = 0; d < 32; ++d) s = fmaf(Wq[d * 32 + a], bk[d], s);
        v_l[a] = s * isq;
    } else if (tid == 320) {                       // c = bq.bk * isq
        float s = 0.f;
        #pragma unroll 8
        for (int d = 0; d < 32; ++d) s = fmaf(bq[d], bk[d], s);
        c_l = s * isq;
    } else if (tid >= 480) {
        int a = tid - 480;
        bp_l[a] = bp[a]; g_l[a] = ln_g[a]; b_l[a] = ln_b[a];
    } else if (tid >= 448) {
        int a = tid - 448;
        bv_l[a] = bv[a]; bo1_l[a] = bo1[a]; bo2_l[a] = bo2[a];
    }
    __syncthreads();

    // ---- octet mapping: lane o owns d = o + 8e (e<4); 8 lanes per row ----
    const int o   = tid & 7;
    const int row = blockIdx.x * RPB + (tid >> 3);
    if (row >= nRows) return;                      // whole octet exits together; no barriers after

    const size_t rowoff = (size_t)row * 256;
    const float* __restrict__ p0 = f1 + rowoff;
    const float* __restrict__ p1 = f4 + rowoff;
    const float* __restrict__ p2 = fD + rowoff;

    // ---- Phase A: fused 3-stream projection, X/Y alternating buffers (no copies) ----
    float acc0[4], acc1[4], acc2[4];
    #pragma unroll
    for (int e = 0; e < 4; ++e) { acc0[e] = 0.f; acc1[e] = 0.f; acc2[e] = 0.f; }

    float4 Xa0 = *(const float4*)(p0),      Xb0 = *(const float4*)(p0 + 4);
    float4 Xa1 = *(const float4*)(p1),      Xb1 = *(const float4*)(p1 + 4);
    float4 Xa2 = *(const float4*)(p2),      Xb2 = *(const float4*)(p2 + 4);
    float4 Ya0 = *(const float4*)(p0 + 8),  Yb0 = *(const float4*)(p0 + 12);
    float4 Ya1 = *(const float4*)(p1 + 8),  Yb1 = *(const float4*)(p1 + 12);
    float4 Ya2 = *(const float4*)(p2 + 8),  Yb2 = *(const float4*)(p2 + 12);

    const float* wbase = &Wp_l[o * WPS];           // rows o+8e at wbase + e*8*WPS

    #pragma unroll 1
    for (int kc = 0; kc < 256; kc += 16) {
        {   // compute even chunk kc from X
            const float* wr = wbase + kc;
            #pragma unroll
            for (int e = 0; e < 4; ++e) {          // banks 4o..4o+3: conflict-free + 8x bcast
                float4 w0 = *(const float4*)(wr + e * (8 * WPS));
                float4 w1 = *(const float4*)(wr + e * (8 * WPS) + 4);
                FMA4(acc0[e], Xa0, w0) FMA4(acc0[e], Xb0, w1)
                FMA4(acc1[e], Xa1, w0) FMA4(acc1[e], Xb1, w1)
                FMA4(acc2[e], Xa2, w0) FMA4(acc2[e], Xb2, w1)
            }
        }
        if (kc + 16 < 256) {                       // refill X <- chunk kc+16
            Xa0 = *(const float4*)(p0 + kc + 16); Xb0 = *(const float4*)(p0 + kc + 20);
            Xa1 = *(const float4*)(p1 + kc + 16); Xb1 = *(const float4*)(p1 + kc + 20);
            Xa2 = *(const float4*)(p2 + kc + 16); Xb2 = *(const float4*)(p2 + kc + 20);
        }
        {   // compute odd chunk kc+8 from Y
            const float* wr = wbase + kc + 8;
            #pragma unroll
            for (int e = 0; e < 4; ++e) {
                float4 w0 = *(const float4*)(wr + e * (8 * WPS));
                float4 w1 = *(const float4*)(wr + e * (8 * WPS) + 4);
                FMA4(acc0[e], Ya0, w0) FMA4(acc0[e], Yb0, w1)
                FMA4(acc1[e], Ya1, w0) FMA4(acc1[e], Yb1, w1)
                FMA4(acc2[e], Ya2, w0) FMA4(acc2[e], Yb2, w1)
            }
        }
        if (kc + 24 < 256) {                       // refill Y <- chunk kc+24
            Ya0 = *(const float4*)(p0 + kc + 24); Yb0 = *(const float4*)(p0 + kc + 28);
            Ya1 = *(const float4*)(p1 + kc + 24); Yb1 = *(const float4*)(p1 + kc + 28);
            Ya2 = *(const float4*)(p2 + kc + 24); Yb2 = *(const float4*)(p2 + kc + 28);
        }
    }

    // ---- bias + ReLU + LayerNorm per stream (octet reduction over 32 dims) ----
    float Xh[3][4];
    float bpe[4], ge[4], be[4];
    #pragma unroll
    for (int e = 0; e < 4; ++e) { bpe[e] = bp_l[o + 8*e]; ge[e] = g_l[o + 8*e]; be[e] = b_l[o + 8*e]; }
    #pragma unroll
    for (int s = 0; s < 3; ++s) {
        float* accp = (s == 0) ? acc0 : (s == 1) ? acc1 : acc2;
        float sm = 0.f, sq = 0.f;
        #pragma unroll
        for (int e = 0; e < 4; ++e) {
            float t = fmaxf(accp[e] + bpe[e], 0.f);
            accp[e] = t; sm += t; sq = fmaf(t, t, sq);
        }
        sm += __shfl_xor(sm, 1); sm += __shfl_xor(sm, 2); sm += __shfl_xor(sm, 4);
        sq += __shfl_xor(sq, 1); sq += __shfl_xor(sq, 2); sq += __shfl_xor(sq, 4);
        float mu  = sm * 0.03125f;
        float var = fmaf(-mu, mu, sq * 0.03125f);
        float inv = rsqrtf(var + 1e-5f);
        #pragma unroll
        for (int e = 0; e < 4; ++e)
            Xh[s][e] = fmaf(ge[e] * (accp[e] - mu), inv, be[e]);
    }

    // ---- scores sc[s][t] = X_s^T A X_t + u.X_t + v.X_s + c ----
    float uX[3], vX[3];
    {
        float uq[4], vq[4];
        #pragma unroll
        for (int e = 0; e < 4; ++e) { uq[e] = u_l[o + 8*e]; vq[e] = v_l[o + 8*e]; }
        #pragma unroll
        for (int t = 0; t < 3; ++t) {
            float us = 0.f, vs = 0.f;
            #pragma unroll
            for (int e = 0; e < 4; ++e) {
                us = fmaf(uq[e], Xh[t][e], us);
                vs = fmaf(vq[e], Xh[t][e], vs);
            }
            us += __shfl_xor(us, 1); us += __shfl_xor(us, 2); us += __shfl_xor(us, 4);
            vs += __shfl_xor(vs, 1); vs += __shfl_xor(vs, 2); vs += __shfl_xor(vs, 4);
            uX[t] = us; vX[t] = vs;
        }
    }

    float sc[9];
    #pragma unroll
    for (int t = 0; t < 3; ++t) {
        float y[4];
        matvec32(A_l, o, Xh[t], y);                // y[e] = (A X_t)[o+8e], full dot
        #pragma unroll
        for (int s = 0; s < 3; ++s) {
            float p = 0.f;
            #pragma unroll
            for (int e = 0; e < 4; ++e) p = fmaf(Xh[s][e], y[e], p);
            sc[s * 3 + t] = p;                     // partial over my 4 dims
        }
    }
    #pragma unroll
    for (int s = 0; s < 3; ++s)
        #pragma unroll
        for (int t = 0; t < 3; ++t) {
            float p = sc[s * 3 + t];
            p += __shfl_xor(p, 1); p += __shfl_xor(p, 2); p += __shfl_xor(p, 4);
            sc[s * 3 + t] = p + uX[t] + vX[s] + c_l;
        }

    // ---- softmax rows; fold V through xb = sum_t g_t X_t ----
    float g0 = 0.f, g1 = 0.f, g2 = 0.f;
    #pragma unroll
    for (int s = 0; s < 3; ++s) {
        float a0 = sc[s*3+0], a1 = sc[s*3+1], a2 = sc[s*3+2];
        float m  = fmaxf(a0, fmaxf(a1, a2));
        float e0 = __expf(a0 - m), e1 = __expf(a1 - m), e2 = __expf(a2 - m);
        float r  = 1.f / (e0 + e1 + e2);
        g0 = fmaf(e0, r, g0); g1 = fmaf(e1, r, g1); g2 = fmaf(e2, r, g2);
    }
    g0 *= (1.f/3.f); g1 *= (1.f/3.f); g2 *= (1.f/3.f);

    float xb[4];
    #pragma unroll
    for (int e = 0; e < 4; ++e)
        xb[e] = fmaf(g0, Xh[0][e], fmaf(g1, Xh[1][e], g2 * Xh[2][e]));

    // ---- pooled = Wv xb + bv ; h1 = relu(Wo1 pooled + bo1) ; o = Wo2 h1 + bo2 + pooled ----
    float t8[4], ph[4], hh[4];
    matvec32(Wv_l, o, xb, t8);
    #pragma unroll
    for (int e = 0; e < 4; ++e) ph[e] = t8[e] + bv_l[o + 8 * e];
    matvec32(Wo1_l, o, ph, t8);
    #pragma unroll
    for (int e = 0; e < 4; ++e) hh[e] = fmaxf(t8[e] + bo1_l[o + 8 * e], 0.f);
    matvec32(Wo2_l, o, hh, t8);

    float fin[4];
    #pragma unroll
    for (int e = 0; e < 4; ++e) fin[e] = t8[e] + bo2_l[o + 8 * e] + ph[e];

    // ---- intra-octet transpose: lane o gathers F[4o..4o+3] -> one coalesced float4 ----
    // F[4o+i] lives on lane sb+i (sb = 4*(o&1)) in slot e = o>>1  (derivation: 4o+i = s + 8e)
    const int sb = 4 * (o & 1);
    float ov[4];
    #pragma unroll
    for (int i = 0; i < 4; ++i) {
        float c0 = __shfl(fin[0], sb + i, 8);
        float c1 = __shfl(fin[1], sb + i, 8);
        float c2 = __shfl(fin[2], sb + i, 8);
        float c3 = __shfl(fin[3], sb + i, 8);
        float lo = (o & 2) ? c1 : c0;              // pick e = o>>1
        float hi = (o & 2) ? c3 : c2;
        ov[i] = (o & 4) ? hi : lo;
    }
    *(float4*)(out + (size_t)row * 32 + 4 * o) = make_float4(ov[0], ov[1], ov[2], ov[3]);
}

extern "C" void kernel_launch(void* const* d_in, const int* in_sizes, int n_in,
                              void* d_out, int out_size, void* d_ws, size_t ws_size,
                              hipStream_t stream) {
    const float* f1   = (const float*)d_in[0];
    const float* f4   = (const float*)d_in[1];
    const float* fD   = (const float*)d_in[2];
    const float* Wp   = (const float*)d_in[3];
    const float* bp   = (const float*)d_in[4];
    const float* ln_g = (const float*)d_in[5];
    const float* ln_b = (const float*)d_in[6];
    const float* Wq   = (const float*)d_in[7];
    const float* bq   = (const float*)d_in[8];
    const float* Wk   = (const float*)d_in[9];
    const float* bk   = (const float*)d_in[10];
    const float* Wv   = (const float*)d_in[11];
    const float* bv   = (const float*)d_in[12];
    const float* Wo1  = (const float*)d_in[13];
    const float* bo1  = (const float*)d_in[14];
    const float* Wo2  = (const float*)d_in[15];
    const float* bo2  = (const float*)d_in[16];

    const int nRows  = in_sizes[0] / 256;
    const int blocks = (nRows + RPB - 1) / RPB;

    msfe_kernel<<<blocks, BLOCK, 0, stream>>>(
        f1, f4, fD, Wp, bp, ln_g, ln_b, Wq, bq, Wk, bk, Wv, bv,
        Wo1, bo1, Wo2, bo2, (float*)d_out, nRows);
}

// Round 6
// 276.274 us; speedup vs baseline: 4.2034x; 3.2438x over previous
//
#include <hip/hip_runtime.h>

#define BLOCK 512
#define RPB   64           // rows per block: 64 rows x 8 lanes (octet) per row
#define WPH   132          // Wp half-tile LDS row stride (floats): 132%32=4 -> octet lanes distinct banks
#define WS    36           // 32x32 weight LDS row stride: 36%32=4 -> <=2-way (free) conflicts

// chained FMA: acc = acc + dot(x4, w4) as 4 serial v_fma
#define FMA4(ACC_, X_, W_) \
    ACC_ = fmaf((X_).x, (W_).x, ACC_); ACC_ = fmaf((X_).y, (W_).y, ACC_); \
    ACC_ = fmaf((X_).z, (W_).z, ACC_); ACC_ = fmaf((X_).w, (W_).w, ACC_);

// Octet matvec: out[d] = sum_j W[d][j]*in[j]; lane o owns d = o+8e (e<4) and holds
// in[jj] = x[o+8jj]. 8 xor-perm phases; W stored with permuted columns:
// col j at (j&7)*4 + (j>>3), so lane (o^p)'s slice (cols (o^p)+8jj) is one float4.
__device__ __forceinline__ void matvec32(const float* __restrict__ WL, const int o,
                                         const float* __restrict__ in, float* __restrict__ outv)
{
    #pragma unroll
    for (int e = 0; e < 4; ++e) outv[e] = 0.f;
    #pragma unroll
    for (int p = 0; p < 8; ++p) {
        float xs[4];
        #pragma unroll
        for (int jj = 0; jj < 4; ++jj)
            xs[jj] = (p == 0) ? in[jj] : __shfl_xor(in[jj], p);
        const float* wb = WL + o * WS + (o ^ p) * 4;
        #pragma unroll
        for (int e = 0; e < 4; ++e) {      // rows o+8e; banks <=2-way (free) + 8x broadcast
            float4 w = *(const float4*)(wb + e * (8 * WS));
            float t = outv[e];
            t = fmaf(w.x, xs[0], t); t = fmaf(w.y, xs[1], t);
            t = fmaf(w.z, xs[2], t); t = fmaf(w.w, xs[3], t);
            outv[e] = t;
        }
    }
}

__global__ void __launch_bounds__(BLOCK)
msfe_kernel(
    const float* __restrict__ f1, const float* __restrict__ f4, const float* __restrict__ fD,
    const float* __restrict__ Wp, const float* __restrict__ bp,
    const float* __restrict__ ln_g, const float* __restrict__ ln_b,
    const float* __restrict__ Wq, const float* __restrict__ bq,
    const float* __restrict__ Wk, const float* __restrict__ bk,
    const float* __restrict__ Wv, const float* __restrict__ bv,
    const float* __restrict__ Wo1, const float* __restrict__ bo1,
    const float* __restrict__ Wo2, const float* __restrict__ bo2,
    float* __restrict__ out, int nRows)
{
    __shared__ float Wp_l[32 * WPH];                       // 16.9 KB: one 128-K half of Wp
    __shared__ float A_l[32 * WS];                         // Wq^T Wk / sqrt(D), permuted cols
    __shared__ float Wv_l[32 * WS], Wo1_l[32 * WS], Wo2_l[32 * WS];  // permuted cols
    __shared__ float bp_l[32], g_l[32], b_l[32], u_l[32], v_l[32];
    __shared__ float bv_l[32], bo1_l[32], bo2_l[32];
    __shared__ float c_l;
    // total ~36.4 KB -> 4 blocks/CU x 8 waves = 32 waves/CU (8/SIMD) at VGPR<=64

    const int tid = threadIdx.x;
    const float isq = 0.17677669529663688f;  // 1/sqrt(32)

    // ---- preamble: attention mats + vectors (independent LDS regions) ----
    if (tid < 256) {
        // stage Wv/Wo1/Wo2, octet col-perm: col j -> (j&7)*4 + (j>>3)
        // thread owns row d, float4 j4 (cols 4j4+m): pos = 16*(j4&1) + (j4>>1) + 4m
        int d = tid >> 3, j4 = tid & 7;
        int base = d * WS + 16 * (j4 & 1) + (j4 >> 1);
        float4 wv = ((const float4*)Wv )[tid];
        float4 w1 = ((const float4*)Wo1)[tid];
        float4 w2 = ((const float4*)Wo2)[tid];
        Wv_l [base] = wv.x; Wv_l [base+4] = wv.y; Wv_l [base+8] = wv.z; Wv_l [base+12] = wv.w;
        Wo1_l[base] = w1.x; Wo1_l[base+4] = w1.y; Wo1_l[base+8] = w1.z; Wo1_l[base+12] = w1.w;
        Wo2_l[base] = w2.x; Wo2_l[base+4] = w2.y; Wo2_l[base+8] = w2.z; Wo2_l[base+12] = w2.w;
        // A = Wq^T Wk * isq (same col-perm), from global (L2-resident)
        float s0 = 0.f, s1 = 0.f, s2 = 0.f, s3 = 0.f;
        #pragma unroll 8
        for (int dd = 0; dd < 32; ++dd) {
            float  wq = Wq[dd * 32 + d];
            float4 wk = *(const float4*)&Wk[dd * 32 + 4 * j4];
            s0 = fmaf(wq, wk.x, s0); s1 = fmaf(wq, wk.y, s1);
            s2 = fmaf(wq, wk.z, s2); s3 = fmaf(wq, wk.w, s3);
        }
        A_l[base] = s0 * isq; A_l[base+4] = s1 * isq; A_l[base+8] = s2 * isq; A_l[base+12] = s3 * isq;
    } else if (tid < 288) {                        // u = (Wk^T bq) * isq
        int a = tid - 256; float s = 0.f;
        #pragma unroll 8
        for (int d = 0; d < 32; ++d) s = fmaf(bq[d], Wk[d * 32 + a], s);
        u_l[a] = s * isq;
    } else if (tid < 320) {                        // v = (Wq^T bk) * isq
        int a = tid - 288; float s = 0.f;
        #pragma unroll 8
        for (int d = 0; d < 32; ++d) s = fmaf(Wq[d * 32 + a], bk[d], s);
        v_l[a] = s * isq;
    } else if (tid == 320) {                       // c = bq.bk * isq
        float s = 0.f;
        #pragma unroll 8
        for (int d = 0; d < 32; ++d) s = fmaf(bq[d], bk[d], s);
        c_l = s * isq;
    } else if (tid >= 480) {
        int a = tid - 480;
        bp_l[a] = bp[a]; g_l[a] = ln_g[a]; b_l[a] = ln_b[a];
    } else if (tid >= 448) {
        int a = tid - 448;
        bv_l[a] = bv[a]; bo1_l[a] = bo1[a]; bo2_l[a] = bo2[a];
    }

    // ---- octet mapping: lane o owns d = o + 8e (e<4); 8 lanes per row ----
    const int o = tid & 7;
    int row = blockIdx.x * RPB + (tid >> 3);
    const bool active = (row < nRows);
    if (!active) row = nRows - 1;                  // clamp: all lanes reach barriers

    const size_t rowoff = (size_t)row * 256;
    const float* wbase = &Wp_l[o * WPH];           // rows o+8e at wbase + e*8*WPH

    float acc0[4], acc1[4], acc2[4];
    #pragma unroll
    for (int e = 0; e < 4; ++e) { acc0[e] = 0.f; acc1[e] = 0.f; acc2[e] = 0.f; }

    // ---- Phase A: two sequential 128-K halves; chunk=4 X/Y alternating buffers ----
    #pragma unroll
    for (int h = 0; h < 2; ++h) {
        if (h) __syncthreads();                    // all waves done reading half 0
        #pragma unroll
        for (int i = 0; i < 2; ++i) {              // stage half h: 1024 float4, coalesced
            int idx = tid + i * BLOCK;
            int d = idx >> 5, k4 = idx & 31;
            *(float4*)&Wp_l[d * WPH + 4 * k4] = ((const float4*)Wp)[d * 64 + 32 * h + k4];
        }
        __syncthreads();

        const float* __restrict__ b0 = f1 + rowoff + 128 * h;
        const float* __restrict__ b1 = f4 + rowoff + 128 * h;
        const float* __restrict__ b2 = fD + rowoff + 128 * h;

        float4 X0 = *(const float4*)(b0),     X1 = *(const float4*)(b1),     X2 = *(const float4*)(b2);
        float4 Y0 = *(const float4*)(b0 + 4), Y1 = *(const float4*)(b1 + 4), Y2 = *(const float4*)(b2 + 4);

        #pragma unroll 1
        for (int kc = 0; kc < 128; kc += 8) {
            {   // compute chunk kc from X
                const float* wr = wbase + kc;
                #pragma unroll
                for (int e = 0; e < 4; ++e) {      // banks 4o..4o+3: conflict-free + 8x bcast
                    float4 w = *(const float4*)(wr + e * (8 * WPH));
                    FMA4(acc0[e], X0, w) FMA4(acc1[e], X1, w) FMA4(acc2[e], X2, w)
                }
            }
            if (kc + 8 < 128) {                    // refill X <- chunk kc+8
                X0 = *(const float4*)(b0 + kc + 8);
                X1 = *(const float4*)(b1 + kc + 8);
                X2 = *(const float4*)(b2 + kc + 8);
            }
            {   // compute chunk kc+4 from Y
                const float* wr = wbase + kc + 4;
                #pragma unroll
                for (int e = 0; e < 4; ++e) {
                    float4 w = *(const float4*)(wr + e * (8 * WPH));
                    FMA4(acc0[e], Y0, w) FMA4(acc1[e], Y1, w) FMA4(acc2[e], Y2, w)
                }
            }
            if (kc + 12 < 128) {                   // refill Y <- chunk kc+12
                Y0 = *(const float4*)(b0 + kc + 12);
                Y1 = *(const float4*)(b1 + kc + 12);
                Y2 = *(const float4*)(b2 + kc + 12);
            }
        }
    }

    // ---- bias + ReLU + LayerNorm per stream (octet reduction over 32 dims) ----
    float Xh[3][4];
    float bpe[4], ge[4], be[4];
    #pragma unroll
    for (int e = 0; e < 4; ++e) { bpe[e] = bp_l[o + 8*e]; ge[e] = g_l[o + 8*e]; be[e] = b_l[o + 8*e]; }
    #pragma unroll
    for (int s = 0; s < 3; ++s) {
        float* accp = (s == 0) ? acc0 : (s == 1) ? acc1 : acc2;
        float sm = 0.f, sq = 0.f;
        #pragma unroll
        for (int e = 0; e < 4; ++e) {
            float t = fmaxf(accp[e] + bpe[e], 0.f);
            accp[e] = t; sm += t; sq = fmaf(t, t, sq);
        }
        sm += __shfl_xor(sm, 1); sm += __shfl_xor(sm, 2); sm += __shfl_xor(sm, 4);
        sq += __shfl_xor(sq, 1); sq += __shfl_xor(sq, 2); sq += __shfl_xor(sq, 4);
        float mu  = sm * 0.03125f;
        float var = fmaf(-mu, mu, sq * 0.03125f);
        float inv = rsqrtf(var + 1e-5f);
        #pragma unroll
        for (int e = 0; e < 4; ++e)
            Xh[s][e] = fmaf(ge[e] * (accp[e] - mu), inv, be[e]);
    }

    // ---- scores sc[s][t] = X_s^T A X_t + u.X_t + v.X_s + c ----
    float uX[3], vX[3];
    {
        float uq[4], vq[4];
        #pragma unroll
        for (int e = 0; e < 4; ++e) { uq[e] = u_l[o + 8*e]; vq[e] = v_l[o + 8*e]; }
        #pragma unroll
        for (int t = 0; t < 3; ++t) {
            float us = 0.f, vs = 0.f;
            #pragma unroll
            for (int e = 0; e < 4; ++e) {
                us = fmaf(uq[e], Xh[t][e], us);
                vs = fmaf(vq[e], Xh[t][e], vs);
            }
            us += __shfl_xor(us, 1); us += __shfl_xor(us, 2); us += __shfl_xor(us, 4);
            vs += __shfl_xor(vs, 1); vs += __shfl_xor(vs, 2); vs += __shfl_xor(vs, 4);
            uX[t] = us; vX[t] = vs;
        }
    }

    float sc[9];
    #pragma unroll
    for (int t = 0; t < 3; ++t) {
        float y[4];
        matvec32(A_l, o, Xh[t], y);                // y[e] = (A X_t)[o+8e], full dot
        #pragma unroll
        for (int s = 0; s < 3; ++s) {
            float p = 0.f;
            #pragma unroll
            for (int e = 0; e < 4; ++e) p = fmaf(Xh[s][e], y[e], p);
            sc[s * 3 + t] = p;                     // partial over my 4 dims
        }
    }
    #pragma unroll
    for (int s = 0; s < 3; ++s)
        #pragma unroll
        for (int t = 0; t < 3; ++t) {
            float p = sc[s * 3 + t];
            p += __shfl_xor(p, 1); p += __shfl_xor(p, 2); p += __shfl_xor(p, 4);
            sc[s * 3 + t] = p + uX[t] + vX[s] + c_l;
        }

    // ---- softmax rows; fold V through xb = sum_t g_t X_t ----
    float g0 = 0.f, g1 = 0.f, g2 = 0.f;
    #pragma unroll
    for (int s = 0; s < 3; ++s) {
        float a0 = sc[s*3+0], a1 = sc[s*3+1], a2 = sc[s*3+2];
        float m  = fmaxf(a0, fmaxf(a1, a2));
        float e0 = __expf(a0 - m), e1 = __expf(a1 - m), e2 = __expf(a2 - m);
        float r  = 1.f / (e0 + e1 + e2);
        g0 = fmaf(e0, r, g0); g1 = fmaf(e1, r, g1); g2 = fmaf(e2, r, g2);
    }
    g0 *= (1.f/3.f); g1 *= (1.f/3.f); g2 *= (1.f/3.f);

    float xb[4];
    #pragma unroll
    for (int e = 0; e < 4; ++e)
        xb[e] = fmaf(g0, Xh[0][e], fmaf(g1, Xh[1][e], g2 * Xh[2][e]));

    // ---- pooled = Wv xb + bv ; h1 = relu(Wo1 pooled + bo1) ; o = Wo2 h1 + bo2 + pooled ----
    float t8[4], ph[4], hh[4];
    matvec32(Wv_l, o, xb, t8);
    #pragma unroll
    for (int e = 0; e < 4; ++e) ph[e] = t8[e] + bv_l[o + 8 * e];
    matvec32(Wo1_l, o, ph, t8);
    #pragma unroll
    for (int e = 0; e < 4; ++e) hh[e] = fmaxf(t8[e] + bo1_l[o + 8 * e], 0.f);
    matvec32(Wo2_l, o, hh, t8);

    float fin[4];
    #pragma unroll
    for (int e = 0; e < 4; ++e) fin[e] = t8[e] + bo2_l[o + 8 * e] + ph[e];

    // ---- intra-octet transpose: lane o gathers F[4o..4o+3] -> one coalesced float4 ----
    // F[4o+i] lives on lane sb+i (sb = 4*(o&1)) in slot e = o>>1
    const int sb = 4 * (o & 1);
    float ov[4];
    #pragma unroll
    for (int i = 0; i < 4; ++i) {
        float c0 = __shfl(fin[0], sb + i, 8);
        float c1 = __shfl(fin[1], sb + i, 8);
        float c2 = __shfl(fin[2], sb + i, 8);
        float c3 = __shfl(fin[3], sb + i, 8);
        float lo = (o & 2) ? c1 : c0;              // pick e = o>>1
        float hi = (o & 2) ? c3 : c2;
        ov[i] = (o & 4) ? hi : lo;
    }
    if (active)
        *(float4*)(out + (size_t)row * 32 + 4 * o) = make_float4(ov[0], ov[1], ov[2], ov[3]);
}

extern "C" void kernel_launch(void* const* d_in, const int* in_sizes, int n_in,
                              void* d_out, int out_size, void* d_ws, size_t ws_size,
                              hipStream_t stream) {
    const float* f1   = (const float*)d_in[0];
    const float* f4   = (const float*)d_in[1];
    const float* fD   = (const float*)d_in[2];
    const float* Wp   = (const float*)d_in[3];
    const float* bp   = (const float*)d_in[4];
    const float* ln_g = (const float*)d_in[5];
    const float* ln_b = (const float*)d_in[6];
    const float* Wq   = (const float*)d_in[7];
    const float* bq   = (const float*)d_in[8];
    const float* Wk   = (const float*)d_in[9];
    const float* bk   = (const float*)d_in[10];
    const float* Wv   = (const float*)d_in[11];
    const float* bv   = (const float*)d_in[12];
    const float* Wo1  = (const float*)d_in[13];
    const float* bo1  = (const float*)d_in[14];
    const float* Wo2  = (const float*)d_in[15];
    const float* bo2  = (const float*)d_in[16];

    const int nRows  = in_sizes[0] / 256;
    const int blocks = (nRows + RPB - 1) / RPB;

    msfe_kernel<<<blocks, BLOCK, 0, stream>>>(
        f1, f4, fD, Wp, bp, ln_g, ln_b, Wq, bq, Wk, bk, Wv, bv,
        Wo1, bo1, Wo2, bo2, (float*)d_out, nRows);
}